// Round 10
// baseline (254.348 us; speedup 1.0000x reference)
//
#include <hip/hip_runtime.h>

#define HW 2304
#define W48 48
#define NT 15              // timestep partials for the atomic spread
#define RS_STRIDE 52       // Rs row stride in floats
#define RS_ROWS 16         // F-local rows 0..15 = query rows yq*12 + (rid-2)
#define RS_SIZE (RS_ROWS * RS_STRIDE)

// ---------------------------------------------------------------------------
// prep: build rec_ext (float4: c0,c1,c2,walls) for all 16 timesteps,
//       build cur0 (frame 0 + walls), copy frame 0 (3ch) to d_out.
// ---------------------------------------------------------------------------
__global__ __launch_bounds__(256) void prep_kernel(
    const float* __restrict__ x, const float* __restrict__ rec,
    const float* __restrict__ walls,
    float4* __restrict__ rec4, float4* __restrict__ cur0,
    float* __restrict__ dout)
{
    int id = blockIdx.x * 256 + threadIdx.x;
    if (id < 16 * HW) {
        int t = id / HW, p = id % HW;
        rec4[id] = make_float4(rec[(t * 3 + 0) * HW + p],
                               rec[(t * 3 + 1) * HW + p],
                               rec[(t * 3 + 2) * HW + p],
                               walls[p]);
    }
    if (id < HW) {
        cur0[id] = make_float4(x[0 * HW + id], x[1 * HW + id], x[2 * HW + id],
                               walls[id]);
    }
    if (id < 3 * HW) {
        dout[id] = x[id];  // frame 0, channels 0..2
    }
}

// ---------------------------------------------------------------------------
// dist v10: block = (t, sy, y-quarter, sx-half), 5760 blocks x 256 threads
// (4 waves). r9's per-thread structure (36 VGPR, bit-identical expressions)
// re-tiled for residency: 8 blocks/CU (2048-thread cap = 100%), 8 independent
// barrier groups/CU, and a 2.8-generation grid for a smooth tail.
//  - A phase: 16 F-rows (12 outputs + 4 halo) x 16 col-groups x 3 px;
//    4-slot NAMED rec ring; bpermute col-halo within 16-lane rows.
//  - C phase: 192 threads (48 cols x 4 row-triples) x 3 outputs, 7 ds_reads.
//  - LDS = double-buffered Rs only (6656 B).
// F/R/D expressions and summation order bit-identical to rounds 2..9.
// ---------------------------------------------------------------------------
__global__ __launch_bounds__(256, 8) void dist_kernel(
    const float4* __restrict__ rec4, const float4* __restrict__ cur4,
    unsigned long long* __restrict__ best_part)
{
    __shared__ float Rs[2 * RS_SIZE];      // 6656 B

    const int tid = threadIdx.x;
    const int b   = blockIdx.x;
    const int t   = b / 384;
    const int rem = b % 384;
    const int sy  = rem >> 3;
    const int q   = rem & 7;
    const int yq  = q >> 1;          // y-quarter: output rows yq*12..yq*12+11
    const int sx0 = (q & 1) * 24;    // sx half: sx0..sx0+23

    // A ownership: F-local row rid (0..15), cols x0..x0+2
    const int rid = tid >> 4;
    const int cA  = tid & 15;
    const int x0  = 3 * cA;
    int qy = yq * 12 + rid - 2;
    if (qy < 0) qy += W48;
    if (qy >= W48) qy -= W48;
    int ry = qy + sy; if (ry >= W48) ry -= W48;

    const int lane  = tid & 63;
    const int addrL = ((lane & ~15) | ((cA + 15) & 15)) << 2;
    const int addrR = ((lane & ~15) | ((cA + 1) & 15)) << 2;

    const float4* curRow = cur4 + qy * W48;
    const float4 cw0 = curRow[x0 + 0];
    const float4 cw1 = curRow[x0 + 1];
    const float4 cw2 = curRow[x0 + 2];

    const float4* recRow = rec4 + t * HW + ry * W48;
    // ring init: slot j holds col (x0 + sx0 + j) % 48
    int cb = x0 + sx0; if (cb >= W48) cb -= W48;
    float4 q0, q1, q2, q3;
    { int c = cb;                          q0 = recRow[c]; }
    { int c = cb + 1; if (c >= W48) c -= W48; q1 = recRow[c]; }
    { int c = cb + 2; if (c >= W48) c -= W48; q2 = recRow[c]; }
    { int c = cb + 3; if (c >= W48) c -= W48; q3 = recRow[c]; }
    int nc = cb + 4; if (nc >= W48) nc -= W48;

    // C ownership (tid < 192): col xc, output rows qyB..qyB+2
    const bool cact = tid < 192;
    const int xc  = tid % W48;
    const int y0C = 3 * (tid / W48);       // 0,3,6,9 for active threads
    const int qyB = yq * 12 + y0C;
    unsigned int mb0 = 0, mb1 = 0, mb2 = 0;
    if (cact) {
        int o0 = qyB + 0 + sy; if (o0 >= W48) o0 -= W48;
        int o1 = qyB + 1 + sy; if (o1 >= W48) o1 -= W48;
        int o2 = qyB + 2 + sy; if (o2 >= W48) o2 -= W48;
        mb0 = (unsigned)(t * HW + o0 * W48);
        mb1 = (unsigned)(t * HW + o1 * W48);
        mb2 = (unsigned)(t * HW + o2 * W48);
    }
    int rx = xc + sx0; if (rx >= W48) rx -= W48;   // candidate col (xc+sx)%48

    unsigned long long bst0 = ~0ULL, bst1 = ~0ULL, bst2 = ~0ULL;

#define DIFF(D, C, Wv) do {                                                 \
        float d0 = (C).x - (Wv).x, d1 = (C).y - (Wv).y,                     \
              d2 = (C).z - (Wv).z, d3 = (C).w - (Wv).w;                     \
        D = d0 * d0 + d1 * d1 + d2 * d2 + d3 * d3;                          \
    } while (0)

#define STEP(P, A0, A1, A2) do {                                            \
        float F0, F1, F2;                                                   \
        DIFF(F0, cw0, A0); DIFF(F1, cw1, A1); DIFF(F2, cw2, A2);            \
        float Fm2 = __int_as_float(                                         \
            __builtin_amdgcn_ds_bpermute(addrL, __float_as_int(F1)));       \
        float Fm1 = __int_as_float(                                         \
            __builtin_amdgcn_ds_bpermute(addrL, __float_as_int(F2)));       \
        float F3  = __int_as_float(                                         \
            __builtin_amdgcn_ds_bpermute(addrR, __float_as_int(F0)));       \
        float F4  = __int_as_float(                                         \
            __builtin_amdgcn_ds_bpermute(addrR, __float_as_int(F1)));       \
        float R0 = Fm2 + Fm1 + F0 + F1 + F2;                                \
        float R1 = Fm1 + F0 + F1 + F2 + F3;                                 \
        float R2 = F0 + F1 + F2 + F3 + F4;                                  \
        {                                                                   \
            float* w = &Rs[(P) * RS_SIZE + rid * RS_STRIDE + x0];           \
            w[0] = R0; w[1] = R1; w[2] = R2;                                \
        }                                                                   \
        A0 = recRow[nc];            /* refill retiring slot */              \
        nc++; if (nc >= W48) nc -= W48;                                     \
        __syncthreads();                                                    \
        if (cact) {                                                         \
            const float* rp = &Rs[(P) * RS_SIZE + y0C * RS_STRIDE + xc];    \
            float rv0 = rp[0],   rv1 = rp[52],  rv2 = rp[104];              \
            float rv3 = rp[156], rv4 = rp[208], rv5 = rp[260];              \
            float rv6 = rp[312];                                            \
            float D0 = rv0 + rv1 + rv2 + rv3 + rv4;                         \
            float D1 = rv1 + rv2 + rv3 + rv4 + rv5;                         \
            float D2 = rv2 + rv3 + rv4 + rv5 + rv6;                         \
            unsigned long long pk;                                          \
            pk = ((unsigned long long)__float_as_uint(D0) << 32) |          \
                 (mb0 + (unsigned)rx);                                      \
            bst0 = pk < bst0 ? pk : bst0;                                   \
            pk = ((unsigned long long)__float_as_uint(D1) << 32) |          \
                 (mb1 + (unsigned)rx);                                      \
            bst1 = pk < bst1 ? pk : bst1;                                   \
            pk = ((unsigned long long)__float_as_uint(D2) << 32) |          \
                 (mb2 + (unsigned)rx);                                      \
            bst2 = pk < bst2 ? pk : bst2;                                   \
        }                                                                   \
        rx++; if (rx >= W48) rx -= W48;                                     \
    } while (0)

    for (int it = 0; it < 6; it++) {
        STEP(0, q0, q1, q2);
        STEP(1, q1, q2, q3);
        STEP(0, q2, q3, q0);
        STEP(1, q3, q0, q1);
    }
#undef STEP
#undef DIFF

    if (cact) {
        unsigned long long* bt = best_part + (size_t)t * HW + qyB * W48 + xc;
        atomicMin(&bt[0 * W48], bst0);
        atomicMin(&bt[1 * W48], bst1);
        atomicMin(&bt[2 * W48], bst2);
    }
}

// ---------------------------------------------------------------------------
// gather: reduce per-t partials; gather center pixel of (t+1) patch; write
// output frame + next carry + per-element sq-error.
// ---------------------------------------------------------------------------
__global__ __launch_bounds__(256) void gather_kernel(
    const unsigned long long* __restrict__ best_part,
    const float4* __restrict__ rec4, const float* __restrict__ x,
    const float* __restrict__ walls,
    float4* __restrict__ curnext, float* __restrict__ dout,
    float* __restrict__ err, int step)
{
    int p = blockIdx.x * 256 + threadIdx.x;
    if (p >= HW) return;
    unsigned long long bestv = ~0ULL;
#pragma unroll
    for (int j = 0; j < NT; j++) {
        unsigned long long v = best_part[(size_t)j * HW + p];
        bestv = v < bestv ? v : bestv;
    }
    unsigned int m = (unsigned int)bestv;
    int t = m / HW, q = m % HW;
    float4 v = rec4[(t + 1) * HW + q];
    curnext[p] = v;
    dout[(step + 1) * 3 * HW + 0 * HW + p] = v.x;
    dout[(step + 1) * 3 * HW + 1 * HW + p] = v.y;
    dout[(step + 1) * 3 * HW + 2 * HW + p] = v.z;
    float t0 = x[((step + 1) * 3 + 0) * HW + p];
    float t1 = x[((step + 1) * 3 + 1) * HW + p];
    float t2 = x[((step + 1) * 3 + 2) * HW + p];
    float t3 = walls[p];
    float e = (v.x - t0) * (v.x - t0) + (v.y - t1) * (v.y - t1) +
              (v.z - t2) * (v.z - t2) + (v.w - t3) * (v.w - t3);
    err[step * HW + p] = e;
}

// ---------------------------------------------------------------------------
// loss: deterministic reduction; loss = total / 18432.
// ---------------------------------------------------------------------------
__global__ __launch_bounds__(256) void loss_kernel(
    const float* __restrict__ err, float* __restrict__ dout)
{
    __shared__ float ssum[256];
    float s = 0.f;
    for (int i = threadIdx.x; i < 2 * HW; i += 256) s += err[i];
    ssum[threadIdx.x] = s;
    __syncthreads();
    for (int w = 128; w > 0; w >>= 1) {
        if (threadIdx.x < w) ssum[threadIdx.x] += ssum[threadIdx.x + w];
        __syncthreads();
    }
    if (threadIdx.x == 0) dout[9 * HW] = ssum[0] / 18432.0f;
}

extern "C" void kernel_launch(void* const* d_in, const int* in_sizes, int n_in,
                              void* d_out, int out_size, void* d_ws,
                              size_t ws_size, hipStream_t stream)
{
    const float* x     = (const float*)d_in[0];
    const float* rec   = (const float*)d_in[1];
    const float* walls = (const float*)d_in[2];
    float* dout = (float*)d_out;

    char* ws = (char*)d_ws;
    float4* rec4 = (float4*)ws;                               // 589824 B
    float4* curb = (float4*)(ws + 589824);                    // 110592 B
    float*  err  = (float*)(ws + 589824 + 110592);            //  18432 B
    unsigned long long* best_part =
        (unsigned long long*)(ws + 589824 + 110592 + 18432);  // 276480 B

    prep_kernel<<<144, 256, 0, stream>>>(x, rec, walls, rec4, curb, dout);
    for (int step = 0; step < 2; step++) {
        hipMemsetAsync(best_part, 0xFF, (size_t)NT * HW * 8, stream);
        dist_kernel<<<NT * W48 * 8, 256, 0, stream>>>(rec4, curb + step * HW,
                                                      best_part);
        gather_kernel<<<9, 256, 0, stream>>>(best_part, rec4, x, walls,
                                             curb + (step + 1) * HW, dout, err,
                                             step);
    }
    loss_kernel<<<1, 256, 0, stream>>>(err, dout);
}

// Round 11
// 172.414 us; speedup vs baseline: 1.4752x; 1.4752x over previous
//
#include <hip/hip_runtime.h>

#define HW 2304
#define W48 48
#define NT 15              // timestep partials for the atomic spread
#define RS_STRIDE 52       // Rs row stride in floats
#define RS_ROWS 16         // F-local rows 0..15 = query rows yq*12 + (rid-2)
#define RS_SIZE (RS_ROWS * RS_STRIDE)

// ---------------------------------------------------------------------------
// prep: build rec_ext (float4: c0,c1,c2,walls) for all 16 timesteps,
//       build cur0 (frame 0 + walls), copy frame 0 (3ch) to d_out.
// ---------------------------------------------------------------------------
__global__ __launch_bounds__(256) void prep_kernel(
    const float* __restrict__ x, const float* __restrict__ rec,
    const float* __restrict__ walls,
    float4* __restrict__ rec4, float4* __restrict__ cur0,
    float* __restrict__ dout)
{
    int id = blockIdx.x * 256 + threadIdx.x;
    if (id < 16 * HW) {
        int t = id / HW, p = id % HW;
        rec4[id] = make_float4(rec[(t * 3 + 0) * HW + p],
                               rec[(t * 3 + 1) * HW + p],
                               rec[(t * 3 + 2) * HW + p],
                               walls[p]);
    }
    if (id < HW) {
        cur0[id] = make_float4(x[0 * HW + id], x[1 * HW + id], x[2 * HW + id],
                               walls[id]);
    }
    if (id < 3 * HW) {
        dout[id] = x[id];  // frame 0, channels 0..2
    }
}

// ---------------------------------------------------------------------------
// dist v11: identical structure to v10 (block = (t, sy, y-quarter, sx-half),
// 5760 blocks x 256 threads), with ONE change: __launch_bounds__(256) with
// NO min-waves hint. v10's (256,8) forced VGPR=32 < the ~36 the state needs
// -> scratch spill (WRITE_SIZE 13->57 MB, dist 77->135 us). Natural
// allocation (~36-40 VGPR) + 6.7 KB LDS still gives 8 blocks/CU via the
// 2048-thread cap = 32 waves, 8 independent barrier groups per CU.
//  - A phase: 16 F-rows (12 outputs + 4 halo) x 16 col-groups x 3 px;
//    4-slot NAMED rec ring; bpermute col-halo within 16-lane rows.
//  - C phase: 192 threads (48 cols x 4 row-triples) x 3 outputs, 7 ds_reads.
// F/R/D expressions and summation order bit-identical to rounds 2..10.
// ---------------------------------------------------------------------------
__global__ __launch_bounds__(256) void dist_kernel(
    const float4* __restrict__ rec4, const float4* __restrict__ cur4,
    unsigned long long* __restrict__ best_part)
{
    __shared__ float Rs[2 * RS_SIZE];      // 6656 B

    const int tid = threadIdx.x;
    const int b   = blockIdx.x;
    const int t   = b / 384;
    const int rem = b % 384;
    const int sy  = rem >> 3;
    const int q   = rem & 7;
    const int yq  = q >> 1;          // y-quarter: output rows yq*12..yq*12+11
    const int sx0 = (q & 1) * 24;    // sx half: sx0..sx0+23

    // A ownership: F-local row rid (0..15), cols x0..x0+2
    const int rid = tid >> 4;
    const int cA  = tid & 15;
    const int x0  = 3 * cA;
    int qy = yq * 12 + rid - 2;
    if (qy < 0) qy += W48;
    if (qy >= W48) qy -= W48;
    int ry = qy + sy; if (ry >= W48) ry -= W48;

    const int lane  = tid & 63;
    const int addrL = ((lane & ~15) | ((cA + 15) & 15)) << 2;
    const int addrR = ((lane & ~15) | ((cA + 1) & 15)) << 2;

    const float4* curRow = cur4 + qy * W48;
    const float4 cw0 = curRow[x0 + 0];
    const float4 cw1 = curRow[x0 + 1];
    const float4 cw2 = curRow[x0 + 2];

    const float4* recRow = rec4 + t * HW + ry * W48;
    // ring init: slot j holds col (x0 + sx0 + j) % 48
    int cb = x0 + sx0; if (cb >= W48) cb -= W48;
    float4 q0, q1, q2, q3;
    { int c = cb;                          q0 = recRow[c]; }
    { int c = cb + 1; if (c >= W48) c -= W48; q1 = recRow[c]; }
    { int c = cb + 2; if (c >= W48) c -= W48; q2 = recRow[c]; }
    { int c = cb + 3; if (c >= W48) c -= W48; q3 = recRow[c]; }
    int nc = cb + 4; if (nc >= W48) nc -= W48;

    // C ownership (tid < 192): col xc, output rows qyB..qyB+2
    const bool cact = tid < 192;
    const int xc  = tid % W48;
    const int y0C = 3 * (tid / W48);       // 0,3,6,9 for active threads
    const int qyB = yq * 12 + y0C;
    unsigned int mb0 = 0, mb1 = 0, mb2 = 0;
    if (cact) {
        int o0 = qyB + 0 + sy; if (o0 >= W48) o0 -= W48;
        int o1 = qyB + 1 + sy; if (o1 >= W48) o1 -= W48;
        int o2 = qyB + 2 + sy; if (o2 >= W48) o2 -= W48;
        mb0 = (unsigned)(t * HW + o0 * W48);
        mb1 = (unsigned)(t * HW + o1 * W48);
        mb2 = (unsigned)(t * HW + o2 * W48);
    }
    int rx = xc + sx0; if (rx >= W48) rx -= W48;   // candidate col (xc+sx)%48

    unsigned long long bst0 = ~0ULL, bst1 = ~0ULL, bst2 = ~0ULL;

#define DIFF(D, C, Wv) do {                                                 \
        float d0 = (C).x - (Wv).x, d1 = (C).y - (Wv).y,                     \
              d2 = (C).z - (Wv).z, d3 = (C).w - (Wv).w;                     \
        D = d0 * d0 + d1 * d1 + d2 * d2 + d3 * d3;                          \
    } while (0)

#define STEP(P, A0, A1, A2) do {                                            \
        float F0, F1, F2;                                                   \
        DIFF(F0, cw0, A0); DIFF(F1, cw1, A1); DIFF(F2, cw2, A2);            \
        float Fm2 = __int_as_float(                                         \
            __builtin_amdgcn_ds_bpermute(addrL, __float_as_int(F1)));       \
        float Fm1 = __int_as_float(                                         \
            __builtin_amdgcn_ds_bpermute(addrL, __float_as_int(F2)));       \
        float F3  = __int_as_float(                                         \
            __builtin_amdgcn_ds_bpermute(addrR, __float_as_int(F0)));       \
        float F4  = __int_as_float(                                         \
            __builtin_amdgcn_ds_bpermute(addrR, __float_as_int(F1)));       \
        float R0 = Fm2 + Fm1 + F0 + F1 + F2;                                \
        float R1 = Fm1 + F0 + F1 + F2 + F3;                                 \
        float R2 = F0 + F1 + F2 + F3 + F4;                                  \
        {                                                                   \
            float* w = &Rs[(P) * RS_SIZE + rid * RS_STRIDE + x0];           \
            w[0] = R0; w[1] = R1; w[2] = R2;                                \
        }                                                                   \
        A0 = recRow[nc];            /* refill retiring slot */              \
        nc++; if (nc >= W48) nc -= W48;                                     \
        __syncthreads();                                                    \
        if (cact) {                                                         \
            const float* rp = &Rs[(P) * RS_SIZE + y0C * RS_STRIDE + xc];    \
            float rv0 = rp[0],   rv1 = rp[52],  rv2 = rp[104];              \
            float rv3 = rp[156], rv4 = rp[208], rv5 = rp[260];              \
            float rv6 = rp[312];                                            \
            float D0 = rv0 + rv1 + rv2 + rv3 + rv4;                         \
            float D1 = rv1 + rv2 + rv3 + rv4 + rv5;                         \
            float D2 = rv2 + rv3 + rv4 + rv5 + rv6;                         \
            unsigned long long pk;                                          \
            pk = ((unsigned long long)__float_as_uint(D0) << 32) |          \
                 (mb0 + (unsigned)rx);                                      \
            bst0 = pk < bst0 ? pk : bst0;                                   \
            pk = ((unsigned long long)__float_as_uint(D1) << 32) |          \
                 (mb1 + (unsigned)rx);                                      \
            bst1 = pk < bst1 ? pk : bst1;                                   \
            pk = ((unsigned long long)__float_as_uint(D2) << 32) |          \
                 (mb2 + (unsigned)rx);                                      \
            bst2 = pk < bst2 ? pk : bst2;                                   \
        }                                                                   \
        rx++; if (rx >= W48) rx -= W48;                                     \
    } while (0)

    for (int it = 0; it < 6; it++) {
        STEP(0, q0, q1, q2);
        STEP(1, q1, q2, q3);
        STEP(0, q2, q3, q0);
        STEP(1, q3, q0, q1);
    }
#undef STEP
#undef DIFF

    if (cact) {
        unsigned long long* bt = best_part + (size_t)t * HW + qyB * W48 + xc;
        atomicMin(&bt[0 * W48], bst0);
        atomicMin(&bt[1 * W48], bst1);
        atomicMin(&bt[2 * W48], bst2);
    }
}

// ---------------------------------------------------------------------------
// gather: reduce per-t partials; gather center pixel of (t+1) patch; write
// output frame + next carry + per-element sq-error.
// ---------------------------------------------------------------------------
__global__ __launch_bounds__(256) void gather_kernel(
    const unsigned long long* __restrict__ best_part,
    const float4* __restrict__ rec4, const float* __restrict__ x,
    const float* __restrict__ walls,
    float4* __restrict__ curnext, float* __restrict__ dout,
    float* __restrict__ err, int step)
{
    int p = blockIdx.x * 256 + threadIdx.x;
    if (p >= HW) return;
    unsigned long long bestv = ~0ULL;
#pragma unroll
    for (int j = 0; j < NT; j++) {
        unsigned long long v = best_part[(size_t)j * HW + p];
        bestv = v < bestv ? v : bestv;
    }
    unsigned int m = (unsigned int)bestv;
    int t = m / HW, q = m % HW;
    float4 v = rec4[(t + 1) * HW + q];
    curnext[p] = v;
    dout[(step + 1) * 3 * HW + 0 * HW + p] = v.x;
    dout[(step + 1) * 3 * HW + 1 * HW + p] = v.y;
    dout[(step + 1) * 3 * HW + 2 * HW + p] = v.z;
    float t0 = x[((step + 1) * 3 + 0) * HW + p];
    float t1 = x[((step + 1) * 3 + 1) * HW + p];
    float t2 = x[((step + 1) * 3 + 2) * HW + p];
    float t3 = walls[p];
    float e = (v.x - t0) * (v.x - t0) + (v.y - t1) * (v.y - t1) +
              (v.z - t2) * (v.z - t2) + (v.w - t3) * (v.w - t3);
    err[step * HW + p] = e;
}

// ---------------------------------------------------------------------------
// loss: deterministic reduction; loss = total / 18432.
// ---------------------------------------------------------------------------
__global__ __launch_bounds__(256) void loss_kernel(
    const float* __restrict__ err, float* __restrict__ dout)
{
    __shared__ float ssum[256];
    float s = 0.f;
    for (int i = threadIdx.x; i < 2 * HW; i += 256) s += err[i];
    ssum[threadIdx.x] = s;
    __syncthreads();
    for (int w = 128; w > 0; w >>= 1) {
        if (threadIdx.x < w) ssum[threadIdx.x] += ssum[threadIdx.x + w];
        __syncthreads();
    }
    if (threadIdx.x == 0) dout[9 * HW] = ssum[0] / 18432.0f;
}

extern "C" void kernel_launch(void* const* d_in, const int* in_sizes, int n_in,
                              void* d_out, int out_size, void* d_ws,
                              size_t ws_size, hipStream_t stream)
{
    const float* x     = (const float*)d_in[0];
    const float* rec   = (const float*)d_in[1];
    const float* walls = (const float*)d_in[2];
    float* dout = (float*)d_out;

    char* ws = (char*)d_ws;
    float4* rec4 = (float4*)ws;                               // 589824 B
    float4* curb = (float4*)(ws + 589824);                    // 110592 B
    float*  err  = (float*)(ws + 589824 + 110592);            //  18432 B
    unsigned long long* best_part =
        (unsigned long long*)(ws + 589824 + 110592 + 18432);  // 276480 B

    prep_kernel<<<144, 256, 0, stream>>>(x, rec, walls, rec4, curb, dout);
    for (int step = 0; step < 2; step++) {
        hipMemsetAsync(best_part, 0xFF, (size_t)NT * HW * 8, stream);
        dist_kernel<<<NT * W48 * 8, 256, 0, stream>>>(rec4, curb + step * HW,
                                                      best_part);
        gather_kernel<<<9, 256, 0, stream>>>(best_part, rec4, x, walls,
                                             curb + (step + 1) * HW, dout, err,
                                             step);
    }
    loss_kernel<<<1, 256, 0, stream>>>(err, dout);
}